// Round 8
// baseline (82.963 us; speedup 1.0000x reference)
//
#include <hip/hip_runtime.h>
#include <stdint.h>

#define NN 50000
#define DD 128
#define PP 6
#define LL 6
#define GN 64          // nodes per block
#define WPAD 136       // bf16 LDS row stride (128+8): 272B rows (17x16B) keep b128 reads 16B-aligned

typedef float f4 __attribute__((ext_vector_type(4)));
typedef short bf16x8 __attribute__((ext_vector_type(8)));

__device__ __forceinline__ uint16_t f2bf(float f) {
  uint32_t u = __float_as_uint(f);
  u = (u + 0x7fffu + ((u >> 16) & 1u)) >> 16;   // RNE
  return (uint16_t)u;
}
__device__ __forceinline__ float bf_lo(uint32_t u) { return __uint_as_float(u << 16); }
__device__ __forceinline__ float bf_hi(uint32_t u) { return __uint_as_float(u & 0xffff0000u); }

// ---- kernel 0: feats f32 -> bf16 (fb) and fc_weight f32 -> bf16 (wb) ----
__global__ __launch_bounds__(256) void k_cvt(const float* __restrict__ feats,
                                             const float* __restrict__ fcw,
                                             uint16_t* __restrict__ fb,
                                             uint16_t* __restrict__ wb,
                                             int n4, int w4) {
  int i = blockIdx.x * 256 + threadIdx.x;
  const float* src; uint16_t* dst; int j;
  if (i < n4)            { src = feats; dst = fb; j = i; }
  else if (i < n4 + w4)  { src = fcw;   dst = wb; j = i - n4; }
  else return;
  f4 v = ((const f4*)src)[j];
  ushort4 o;
  o.x = f2bf(v.x); o.y = f2bf(v.y); o.z = f2bf(v.z); o.w = f2bf(v.w);
  ((ushort4*)dst)[j] = o;
}

// ---- fused kernel: gather-weighted accumulate -> LDS tile -> MFMA fc (W direct from global) -> out
__global__ __launch_bounds__(256) void k_gfc(
    const uint16_t* __restrict__ fb,     // (NN, DD) bf16
    const int* __restrict__ paths,       // (PP, NN, LL) int32
    const float* __restrict__ w,         // (LL, DD) f32
    const uint16_t* __restrict__ wb,     // (DD, DD) bf16, row-major (o, d) — L2-hot, read direct
    float* __restrict__ out) {           // (NN, DD) f32
  __shared__ int sidx[PP * GN * LL];     // 9216 B
  __shared__ uint16_t sA[GN * WPAD];     // 17408 B   (total 26.6 KB -> ~5 blocks/CU)
  const int t = threadIdx.x;
  const int nb = blockIdx.x * GN;

  // stage indices (coalesced)
  #pragma unroll
  for (int s = 0; s < 9; ++s) {          // 2304 / 256
    const int i = s * 256 + t;
    const int p = i / (GN * LL);
    const int rem = i - p * (GN * LL);
    const long g = (long)nb * LL + rem;
    int val = 0;
    if (g < (long)NN * LL) val = paths[(size_t)p * NN * LL + g];
    sidx[i] = val;
  }

  const int lane = t & 31;
  const int grp  = t >> 5;               // 0..7
  const int d0   = lane * 4;

  const float sc = 1.f / 6.f;
  f4 wl[LL];
  #pragma unroll
  for (int l = 0; l < LL; ++l) {
    f4 v = *(const f4*)(w + l * DD + d0);
    wl[l].x = v.x * sc; wl[l].y = v.y * sc; wl[l].z = v.z * sc; wl[l].w = v.w * sc;
  }

  __syncthreads();

  // gather: 8 nodes per 32-lane group, 36 row-gathers in flight per node
  #pragma unroll 1
  for (int s = 0; s < 8; ++s) {
    const int ni = grp * 8 + s;
    uint2 v[PP * LL];
    #pragma unroll
    for (int p = 0; p < PP; ++p)
      #pragma unroll
      for (int l = 0; l < LL; ++l) {
        const int idx = sidx[(p * GN + ni) * LL + l];
        v[p * LL + l] = *(const uint2*)(fb + (size_t)idx * DD + d0);  // 4 bf16
      }
    f4 a = {0.f, 0.f, 0.f, 0.f};
    #pragma unroll
    for (int p = 0; p < PP; ++p)
      #pragma unroll
      for (int l = 0; l < LL; ++l) {
        const uint2 u = v[p * LL + l];
        a.x = fmaf(wl[l].x, bf_lo(u.x), a.x);
        a.y = fmaf(wl[l].y, bf_hi(u.x), a.y);
        a.z = fmaf(wl[l].z, bf_lo(u.y), a.z);
        a.w = fmaf(wl[l].w, bf_hi(u.y), a.w);
      }
    ushort4 o;
    o.x = f2bf(a.x); o.y = f2bf(a.y); o.z = f2bf(a.z); o.w = f2bf(a.w);
    *(ushort4*)(sA + ni * WPAD + d0) = o;   // tail rows harmless; guarded at out-store
  }

  __syncthreads();

  // MFMA fc: wave wv owns rows wv*16..wv*16+15; B fragments read direct from global (L2-hot)
  const int wv = t >> 6;                  // wave 0..3
  const int l  = t & 63;
  const int lr = l & 15;                  // A-row / B-col / D-col
  const int hk = (l >> 4) * 8;            // k sub-offset

  bf16x8 afrag[4];
  #pragma unroll
  for (int k0 = 0; k0 < 4; ++k0)
    afrag[k0] = *(bf16x8*)(sA + (wv * 16 + lr) * WPAD + k0 * 32 + hk);

  #pragma unroll
  for (int o = 0; o < 8; ++o) {
    f4 dacc = {0.f, 0.f, 0.f, 0.f};
    #pragma unroll
    for (int k0 = 0; k0 < 4; ++k0) {
      bf16x8 bfrag = *(const bf16x8*)(wb + (size_t)(o * 16 + lr) * DD + k0 * 32 + hk);
      dacc = __builtin_amdgcn_mfma_f32_16x16x32_bf16(afrag[k0], bfrag, dacc, 0, 0, 0);
    }
    const int col = o * 16 + lr;
    #pragma unroll
    for (int r = 0; r < 4; ++r) {
      const int n = nb + wv * 16 + (l >> 4) * 4 + r;
      if (n < NN) out[(size_t)n * DD + col] = fmaxf(dacc[r], 0.f);
    }
  }
}

extern "C" void kernel_launch(void* const* d_in, const int* in_sizes, int n_in,
                              void* d_out, int out_size, void* d_ws, size_t ws_size,
                              hipStream_t stream) {
  const float* feats = (const float*)d_in[0];
  const int*   paths = (const int*)d_in[1];       // int32 (jax x64 disabled)
  const float* pw1   = (const float*)d_in[4];     // (1,6,128)
  const float* fcw   = (const float*)d_in[6];     // (128,128)
  float* out = (float*)d_out;

  uint16_t* fb = (uint16_t*)d_ws;                                  // 12.8 MB
  uint16_t* wb = (uint16_t*)((char*)d_ws + (size_t)NN * DD * 2);   // 32 KB

  const int n4 = NN * DD / 4;      // 1,600,000
  const int w4 = DD * DD / 4;      // 4,096
  k_cvt<<<(n4 + w4 + 255) / 256, 256, 0, stream>>>(feats, fcw, fb, wb, n4, w4);
  k_gfc<<<(NN + GN - 1) / GN, 256, 0, stream>>>(fb, paths, pw1, wb, out);
}

// Round 9
// 75.962 us; speedup vs baseline: 1.0922x; 1.0922x over previous
//
#include <hip/hip_runtime.h>
#include <stdint.h>

#define NN 50000
#define DD 128
#define PP 6
#define LL 6
#define GN 64          // nodes per block
#define WPAD 136       // bf16 LDS row stride (128+8): 272B rows (17x16B) keep b128 reads 16B-aligned

typedef float f4 __attribute__((ext_vector_type(4)));
typedef short bf16x8 __attribute__((ext_vector_type(8)));

__device__ __forceinline__ uint16_t f2bf(float f) {
  uint32_t u = __float_as_uint(f);
  u = (u + 0x7fffu + ((u >> 16) & 1u)) >> 16;   // RNE
  return (uint16_t)u;
}
__device__ __forceinline__ float bf_lo(uint32_t u) { return __uint_as_float(u << 16); }
__device__ __forceinline__ float bf_hi(uint32_t u) { return __uint_as_float(u & 0xffff0000u); }

// ---- kernel 0: feats f32 -> bf16 (fb) and fc_weight f32 -> bf16 (wb) ----
__global__ __launch_bounds__(256) void k_cvt(const float* __restrict__ feats,
                                             const float* __restrict__ fcw,
                                             uint16_t* __restrict__ fb,
                                             uint16_t* __restrict__ wb,
                                             int n4, int w4) {
  int i = blockIdx.x * 256 + threadIdx.x;
  const float* src; uint16_t* dst; int j;
  if (i < n4)            { src = feats; dst = fb; j = i; }
  else if (i < n4 + w4)  { src = fcw;   dst = wb; j = i - n4; }
  else return;
  f4 v = ((const f4*)src)[j];
  ushort4 o;
  o.x = f2bf(v.x); o.y = f2bf(v.y); o.z = f2bf(v.z); o.w = f2bf(v.w);
  ((ushort4*)dst)[j] = o;
}

// ---- fused kernel: gather-weighted accumulate -> LDS tile -> MFMA fc -> out
// No barrier between gather and fc: wave wv writes exactly sA rows 16wv..16wv+15
// (groups 2wv,2wv+1 -> ni = grp*8+s) and its fc reads exactly those rows.
__global__ __launch_bounds__(256) void k_gfc(
    const uint16_t* __restrict__ fb,     // (NN, DD) bf16
    const int* __restrict__ paths,       // (PP, NN, LL) int32
    const float* __restrict__ w,         // (LL, DD) f32
    const uint16_t* __restrict__ wb,     // (DD, DD) bf16, row-major (o, d)
    float* __restrict__ out) {           // (NN, DD) f32
  __shared__ int sidx[PP * GN * LL];     // 9216 B
  __shared__ uint16_t sA[GN * WPAD];     // 17408 B
  __shared__ uint16_t sW[DD * WPAD];     // 34816 B   (total 60 KiB)
  const int t = threadIdx.x;
  const int nb = blockIdx.x * GN;

  // stage indices (coalesced)
  #pragma unroll
  for (int s = 0; s < 9; ++s) {          // 2304 / 256
    const int i = s * 256 + t;
    const int p = i / (GN * LL);
    const int rem = i - p * (GN * LL);
    const long g = (long)nb * LL + rem;
    int val = 0;
    if (g < (long)NN * LL) val = paths[(size_t)p * NN * LL + g];
    sidx[i] = val;
  }
  // stage W tile 128x128 bf16 (coalesced uint4) — load-bearing vs direct-global (round 8: -7us)
  #pragma unroll
  for (int it = 0; it < 8; ++it) {
    const int chunk = it * 256 + t;      // 2048 chunks of 8 bf16
    const int row = chunk >> 4, c8 = chunk & 15;
    uint4 v = *(const uint4*)(wb + (size_t)row * DD + c8 * 8);
    *(uint4*)(sW + row * WPAD + c8 * 8) = v;
  }

  const int lane = t & 31;
  const int grp  = t >> 5;               // 0..7
  const int d0   = lane * 4;

  const float sc = 1.f / 6.f;
  f4 wl[LL];
  #pragma unroll
  for (int l = 0; l < LL; ++l) {
    f4 v = *(const f4*)(w + l * DD + d0);
    wl[l].x = v.x * sc; wl[l].y = v.y * sc; wl[l].z = v.z * sc; wl[l].w = v.w * sc;
  }

  __syncthreads();                       // sidx + sW ready (the only block-wide dependency)

  // gather: 8 nodes per 32-lane group, 36 row-gathers in flight per node
  #pragma unroll 1
  for (int s = 0; s < 8; ++s) {
    const int ni = grp * 8 + s;
    uint2 v[PP * LL];
    #pragma unroll
    for (int p = 0; p < PP; ++p)
      #pragma unroll
      for (int l = 0; l < LL; ++l) {
        const int idx = sidx[(p * GN + ni) * LL + l];
        v[p * LL + l] = *(const uint2*)(fb + (size_t)idx * DD + d0);  // 4 bf16
      }
    f4 a = {0.f, 0.f, 0.f, 0.f};
    #pragma unroll
    for (int p = 0; p < PP; ++p)
      #pragma unroll
      for (int l = 0; l < LL; ++l) {
        const uint2 u = v[p * LL + l];
        a.x = fmaf(wl[l].x, bf_lo(u.x), a.x);
        a.y = fmaf(wl[l].y, bf_hi(u.x), a.y);
        a.z = fmaf(wl[l].z, bf_lo(u.y), a.z);
        a.w = fmaf(wl[l].w, bf_hi(u.y), a.w);
      }
    ushort4 o;
    o.x = f2bf(a.x); o.y = f2bf(a.y); o.z = f2bf(a.z); o.w = f2bf(a.w);
    *(ushort4*)(sA + ni * WPAD + d0) = o;   // tail rows harmless; guarded at out-store
  }

  // NO barrier: each wave reads back only the sA rows it just wrote (lgkmcnt-ordered)

  // MFMA fc: wave wv owns rows wv*16..wv*16+15 (round-6 validated mapping)
  const int wv = t >> 6;                  // wave 0..3
  const int l  = t & 63;
  const int lr = l & 15;                  // A-row / B-col / D-col
  const int hk = (l >> 4) * 8;            // k sub-offset

  bf16x8 afrag[4];
  #pragma unroll
  for (int k0 = 0; k0 < 4; ++k0)
    afrag[k0] = *(bf16x8*)(sA + (wv * 16 + lr) * WPAD + k0 * 32 + hk);

  #pragma unroll
  for (int o = 0; o < 8; ++o) {
    f4 dacc = {0.f, 0.f, 0.f, 0.f};
    #pragma unroll
    for (int k0 = 0; k0 < 4; ++k0) {
      bf16x8 bfrag = *(bf16x8*)(sW + (o * 16 + lr) * WPAD + k0 * 32 + hk);
      dacc = __builtin_amdgcn_mfma_f32_16x16x32_bf16(afrag[k0], bfrag, dacc, 0, 0, 0);
    }
    const int col = o * 16 + lr;
    #pragma unroll
    for (int r = 0; r < 4; ++r) {
      const int n = nb + wv * 16 + (l >> 4) * 4 + r;
      if (n < NN) out[(size_t)n * DD + col] = fmaxf(dacc[r], 0.f);
    }
  }
}

extern "C" void kernel_launch(void* const* d_in, const int* in_sizes, int n_in,
                              void* d_out, int out_size, void* d_ws, size_t ws_size,
                              hipStream_t stream) {
  const float* feats = (const float*)d_in[0];
  const int*   paths = (const int*)d_in[1];       // int32 (jax x64 disabled)
  const float* pw1   = (const float*)d_in[4];     // (1,6,128)
  const float* fcw   = (const float*)d_in[6];     // (128,128)
  float* out = (float*)d_out;

  uint16_t* fb = (uint16_t*)d_ws;                                  // 12.8 MB
  uint16_t* wb = (uint16_t*)((char*)d_ws + (size_t)NN * DD * 2);   // 32 KB

  const int n4 = NN * DD / 4;      // 1,600,000
  const int w4 = DD * DD / 4;      // 4,096
  k_cvt<<<(n4 + w4 + 255) / 256, 256, 0, stream>>>(feats, fcw, fb, wb, n4, w4);
  k_gfc<<<(NN + GN - 1) / GN, 256, 0, stream>>>(fb, paths, pw1, wb, out);
}